// Round 1
// baseline (56.607 us; speedup 1.0000x reference)
//
#include <hip/hip_runtime.h>
#include <hip/hip_bf16.h>

// Reference shape facts:
//   xs = arange(30, 400) -> N = 370 elements, fp32 output
//   inputs: x[1], y[1] fp32
//   out[i] = yv[i] / max(yv) where
//     idx_i  = argmin_j (t_j - xs_i)   (signed diff, first-min-index on tie)
//     f_i    = t_{idx_i}
//     d_i    = (xs_i - f_i)^2
//     yv_i   = d_i > 10 ? 0 : (10 - d_i)^2
//
// Latency-bound: single dispatch, single block (384 thr = 6 waves), fused
// max-reduction via wave shuffle + LDS.

#define N_OUT 370
#define NTHREADS 384  // 6 waves of 64

__global__ __launch_bounds__(NTHREADS) void freq_codebook_kernel(
    const float* __restrict__ x, const float* __restrict__ y,
    float* __restrict__ out) {
  const int i = threadIdx.x;

  const float t0 = x[0];
  const float t1 = y[0];

  const float xs = 30.0f + (float)i;

  // argmin over signed diffs [t0 - xs, t1 - xs]; first index wins ties
  const float d0 = t0 - xs;
  const float d1 = t1 - xs;
  const float f = (d1 < d0) ? t1 : t0;

  float d = xs - f;
  d = d * d;
  const float w = 10.0f - d;
  const float yv = (d > 10.0f) ? 0.0f : w * w;

  // Block-wide max. yv >= 0 always, so pad lanes (i >= 370) contribute 0,
  // which is the identity here iff all yv==0 -> max 0 either way (matches ref).
  float v = (i < N_OUT) ? yv : 0.0f;

  // wave (64-lane) butterfly max
  #pragma unroll
  for (int o = 32; o > 0; o >>= 1) v = fmaxf(v, __shfl_xor(v, o, 64));

  __shared__ float smax[NTHREADS / 64];
  const int wid = i >> 6;
  if ((i & 63) == 0) smax[wid] = v;
  __syncthreads();

  float m = smax[0];
  #pragma unroll
  for (int wgt = 1; wgt < NTHREADS / 64; ++wgt) m = fmaxf(m, smax[wgt]);

  if (i < N_OUT) out[i] = yv / m;
}

extern "C" void kernel_launch(void* const* d_in, const int* in_sizes, int n_in,
                              void* d_out, int out_size, void* d_ws,
                              size_t ws_size, hipStream_t stream) {
  const float* x = (const float*)d_in[0];
  const float* y = (const float*)d_in[1];
  float* out = (float*)d_out;
  freq_codebook_kernel<<<dim3(1), dim3(NTHREADS), 0, stream>>>(x, y, out);
}